// Round 7
// baseline (119.059 us; speedup 1.0000x reference)
//
#include <hip/hip_runtime.h>
#include <cstddef>

typedef unsigned int uint;
typedef _Float16 v8h __attribute__((ext_vector_type(8)));
typedef float v4f __attribute__((ext_vector_type(4)));
typedef __fp16 fp16v2 __attribute__((ext_vector_type(2)));
typedef unsigned short us2v __attribute__((ext_vector_type(2)));

union U32H2 { uint u; fp16v2 g; us2v s; };
union Frag8 { uint4 u4; uint u[4]; v8h h; };  // 8 fp16 = 4 VGPRs (MFMA A/B frag)

// pack two fp32 -> fp16 pair (v_cvt_pkrtz)
__device__ __forceinline__ uint pkh2(float a, float b) {
  U32H2 v; v.g = __builtin_amdgcn_cvt_pkrtz(a, b); return v.u;
}
// packed max on u32-carried fp16 pairs; valid for NON-NEGATIVE fp16 (ReLU'd y):
// fp16 ordering == unsigned ordering => v_pk_max_u16.
__device__ __forceinline__ uint hmax2u(uint a, uint b) {
  U32H2 x, y, r; x.u = a; y.u = b;
  r.s = __builtin_elementwise_max(x.s, y.s);
  return r.u;
}

// ---------------------------------------------------------------------------
// K1: y[b,n,:] = relu(W1 @ x[b,:,n] + b1), fp16 node-major rows (128 B).
// MFMA 16x16x32_f16; epilogue stores DIRECTLY from C-layout (d = w*16+q*4+r
// is contiguous per lane -> uint2 stores; 4 waves fill each 128 B row, L2
// write-merges). No transpose LDS, one __syncthreads.
// ---------------------------------------------------------------------------
__global__ __launch_bounds__(256, 6) void k1_node_mlp(
    const float* __restrict__ x, const float* __restrict__ W1,
    const float* __restrict__ b1, uint* __restrict__ y, int N)
{
  __shared__ __align__(16) uint xlds[64 * 36];  // [n][c-pair], stride 36 dw
  const int t = threadIdx.x;
  const int nblk = (N + 63) >> 6;
  const int b = blockIdx.x / nblk;
  const int n0 = (blockIdx.x % nblk) << 6;
  const int lane = t & 63;
  const int w = t >> 6;          // wave id -> d-strip
  const int node = t >> 2;       // staging row
  const int cg = t & 3;          // 16-channel group

  // ---- x staging: thread covers c = cg*16..+15 of node's row
  {
    const bool valid = (n0 + node) < N;
    const float* xp = x + (size_t)b * 64 * N + n0 + node;
    float xv[16];
#pragma unroll
    for (int i = 0; i < 16; ++i)
      xv[i] = valid ? xp[(size_t)(cg * 16 + i) * N] : 0.0f;
    uint4 p0, p1;
    p0.x = pkh2(xv[0], xv[1]);   p0.y = pkh2(xv[2], xv[3]);
    p0.z = pkh2(xv[4], xv[5]);   p0.w = pkh2(xv[6], xv[7]);
    p1.x = pkh2(xv[8], xv[9]);   p1.y = pkh2(xv[10], xv[11]);
    p1.z = pkh2(xv[12], xv[13]); p1.w = pkh2(xv[14], xv[15]);
    uint* dst = xlds + node * 36 + cg * 8;
    *(uint4*)dst = p0;
    *(uint4*)(dst + 4) = p1;
  }

  // ---- A-frags from W1 (L2-hot): row m = lane&15, k = (lane>>4)*8 + j
  Frag8 af[2];
  {
    const int d_row = w * 16 + (lane & 15);
    const int kb = (lane >> 4) * 8;
    const float* wp = W1 + d_row * 64 + kb;
#pragma unroll
    for (int kk = 0; kk < 2; ++kk) {
      const float4 fa = *(const float4*)(wp + kk * 32);
      const float4 fb = *(const float4*)(wp + kk * 32 + 4);
      af[kk].u4.x = pkh2(fa.x, fa.y);
      af[kk].u4.y = pkh2(fa.z, fa.w);
      af[kk].u4.z = pkh2(fb.x, fb.y);
      af[kk].u4.w = pkh2(fb.z, fb.w);
    }
  }
  __syncthreads();

  // ---- MFMA: D[d, n] per wave: d-strip = w*16, 4 n-tiles x 2 k-steps
  const int q = lane >> 4;
  const int cidx = lane & 15;
  v4f acc[4];
  {
    v4f bi;
#pragma unroll
    for (int r = 0; r < 4; ++r) bi[r] = b1[w * 16 + q * 4 + r];
#pragma unroll
    for (int nt = 0; nt < 4; ++nt) acc[nt] = bi;
  }
#pragma unroll
  for (int nt = 0; nt < 4; ++nt) {
#pragma unroll
    for (int kk = 0; kk < 2; ++kk) {
      Frag8 bf;
      bf.u4 = *(const uint4*)(xlds + (nt * 16 + cidx) * 36 + kk * 16 + q * 4);
      acc[nt] = __builtin_amdgcn_mfma_f32_16x16x32_f16(af[kk].h, bf.h, acc[nt], 0, 0, 0);
    }
  }

  // ---- direct epilogue: relu, pack, 8 B store (channels w*16+q*4 .. +3)
#pragma unroll
  for (int nt = 0; nt < 4; ++nt) {
    const int n = n0 + nt * 16 + cidx;
    if (n < N) {
      uint2 v;
      v.x = pkh2(fmaxf(acc[nt][0], 0.f), fmaxf(acc[nt][1], 0.f));
      v.y = pkh2(fmaxf(acc[nt][2], 0.f), fmaxf(acc[nt][3], 0.f));
      *(uint2*)(y + ((size_t)b * N + n) * 32 + w * 8 + q * 2) = v;
    }
  }
}

// ---------------------------------------------------------------------------
// K2: gather-max over fp16 y rows + out = relu(W2 @ [x; m] + b2) via MFMA.
// B-tile [64 n][128 c] fp16 in LDS (stride 272 B); A = W2 global->frags.
// XCD swizzle: b=0 tiles on XCD slots 0-3, b=1 on 4-7 -> per-XCD gather
// working set = one 6.4 MB y half instead of both.
// 18-deep single-batch gather (all 9 rows x 32 B in flight).
// ---------------------------------------------------------------------------
__global__ __launch_bounds__(256, 4) void k2_gather_out(
    const float* __restrict__ x, const int* __restrict__ eidx,
    const uint* __restrict__ y, const float* __restrict__ W2,
    const float* __restrict__ b2, float* __restrict__ out,
    int N, int K, int nblk_pad)
{
  __shared__ __align__(16) uint blds[64 * 68];  // [n][c-pair], stride 68 dw
  const int t = threadIdx.x;
  const int nblk = (N + 63) >> 6;
  // XCD-aware demux: slot = g&7 -> b = slot>>2; tile = (g>>3)*4 + (slot&3)
  const int g = blockIdx.x;
  const int slot = g & 7;
  const int b = slot >> 2;
  const int tile = ((g >> 3) << 2) + (slot & 3);
  if (tile >= nblk) return;  // padding block (nblk_pad > nblk)
  const int n0 = tile << 6;
  const int lane = t & 63;
  const int w = t >> 6;
  const int node = t >> 2;   // staging/gather row; 4 adjacent lanes = 4 c-segs
  const int cg = t & 3;
  const int n = n0 + node;

  // int64 vs int32 layout: little-endian int64 => odd words all zero (L2-hot)
  const bool is64 = (__ballot(eidx[2 * lane + 1] == 0) == ~0ull);

  // ---- neighbor indices
  int jj[9];
  const bool act = (n < N) && (K == 9);
  if (act) {
    const size_t r = (size_t)b * N + n;
    if (is64) {
      const uint2* p = (const uint2*)eidx + r * 9;
#pragma unroll
      for (int k = 0; k < 9; ++k) jj[k] = (int)p[k].x;
    } else {
      const int* p = eidx + r * 9;
#pragma unroll
      for (int k = 0; k < 9; ++k) jj[k] = p[k];
    }
  }

  // ---- x staging -> blds rows, c in [0,64)
  {
    const bool valid = n < N;
    const float* xp = x + (size_t)b * 64 * N + n0 + node;
    float xv[16];
#pragma unroll
    for (int i = 0; i < 16; ++i)
      xv[i] = valid ? xp[(size_t)(cg * 16 + i) * N] : 0.0f;
    uint4 p0, p1;
    p0.x = pkh2(xv[0], xv[1]);   p0.y = pkh2(xv[2], xv[3]);
    p0.z = pkh2(xv[4], xv[5]);   p0.w = pkh2(xv[6], xv[7]);
    p1.x = pkh2(xv[8], xv[9]);   p1.y = pkh2(xv[10], xv[11]);
    p1.z = pkh2(xv[12], xv[13]); p1.w = pkh2(xv[14], xv[15]);
    uint* dst = blds + node * 68 + cg * 8;
    *(uint4*)dst = p0;
    *(uint4*)(dst + 4) = p1;
  }

  // ---- A-frags from W2 (global, L2-hot)
  Frag8 af[4];
  {
    const int o_row = w * 16 + (lane & 15);
    const int kb = (lane >> 4) * 8;
    const float* wp = W2 + o_row * 128 + kb;
#pragma unroll
    for (int kk = 0; kk < 4; ++kk) {
      const float4 fa = *(const float4*)(wp + kk * 32);
      const float4 fb = *(const float4*)(wp + kk * 32 + 4);
      af[kk].u4.x = pkh2(fa.x, fa.y);
      af[kk].u4.y = pkh2(fa.z, fa.w);
      af[kk].u4.z = pkh2(fb.x, fb.y);
      af[kk].u4.w = pkh2(fb.z, fb.w);
    }
  }

  // ---- gather-max: thread covers 32 B c-seg cg of its node's 9 neighbor
  // rows; ALL 18 uint4 loads issued in one batch (max MLP).
  uint m[8] = {0, 0, 0, 0, 0, 0, 0, 0};
  if (act) {
    const uint* yb = y + (size_t)b * N * 32 + cg * 8;
    uint4 ga[9], gb[9];
#pragma unroll
    for (int k = 0; k < 9; ++k) {
      const uint* base = yb + (size_t)jj[k] * 32;
      ga[k] = *(const uint4*)base;
      gb[k] = *(const uint4*)(base + 4);
    }
#pragma unroll
    for (int k = 0; k < 9; ++k) {
      m[0] = hmax2u(m[0], ga[k].x); m[1] = hmax2u(m[1], ga[k].y);
      m[2] = hmax2u(m[2], ga[k].z); m[3] = hmax2u(m[3], ga[k].w);
      m[4] = hmax2u(m[4], gb[k].x); m[5] = hmax2u(m[5], gb[k].y);
      m[6] = hmax2u(m[6], gb[k].z); m[7] = hmax2u(m[7], gb[k].w);
    }
  } else if (n < N) {  // generic-K fallback
    const size_t r = (size_t)b * N + n;
    const uint* yb = y + (size_t)b * N * 32 + cg * 8;
    for (int k = 0; k < K; ++k) {
      const int j = is64 ? (int)((const uint2*)eidx + r * K)[k].x
                         : (eidx + r * K)[k];
      const uint* base = yb + (size_t)j * 32;
      const uint4 a0 = *(const uint4*)base, a1 = *(const uint4*)(base + 4);
      m[0] = hmax2u(m[0], a0.x); m[1] = hmax2u(m[1], a0.y);
      m[2] = hmax2u(m[2], a0.z); m[3] = hmax2u(m[3], a0.w);
      m[4] = hmax2u(m[4], a1.x); m[5] = hmax2u(m[5], a1.y);
      m[6] = hmax2u(m[6], a1.z); m[7] = hmax2u(m[7], a1.w);
    }
  }
  {
    uint* dst = blds + node * 68 + 32 + cg * 8;  // c in [64,128)
    uint4 v0; v0.x = m[0]; v0.y = m[1]; v0.z = m[2]; v0.w = m[3];
    uint4 v1; v1.x = m[4]; v1.y = m[5]; v1.z = m[6]; v1.w = m[7];
    *(uint4*)dst = v0;
    *(uint4*)(dst + 4) = v1;
  }
  __syncthreads();

  // ---- MFMA: D[o, n] per wave: o-strip w*16, 4 n-tiles x 4 k-steps
  const int q = lane >> 4;
  const int cidx = lane & 15;
  const int o0 = w * 16;
  v4f acc[4];
  {
    v4f bi;
#pragma unroll
    for (int r = 0; r < 4; ++r) bi[r] = b2[o0 + q * 4 + r];
#pragma unroll
    for (int nt = 0; nt < 4; ++nt) acc[nt] = bi;
  }
#pragma unroll
  for (int nt = 0; nt < 4; ++nt) {
#pragma unroll
    for (int kk = 0; kk < 4; ++kk) {
      Frag8 bf;
      bf.u4 = *(const uint4*)(blds + (nt * 16 + cidx) * 68 + kk * 16 + q * 4);
      acc[nt] = __builtin_amdgcn_mfma_f32_16x16x32_f16(af[kk].h, bf.h, acc[nt], 0, 0, 0);
    }
  }

  // ---- epilogue: relu + store; lanes cidx consecutive -> 64 B segments
#pragma unroll
  for (int nt = 0; nt < 4; ++nt) {
    const int nn = n0 + nt * 16 + cidx;
    if (nn < N) {
#pragma unroll
      for (int r = 0; r < 4; ++r) {
        const int o = o0 + q * 4 + r;
        out[(size_t)(b * 64 + o) * N + nn] = fmaxf(acc[nt][r], 0.f);
      }
    }
  }
}

extern "C" void kernel_launch(void* const* d_in, const int* in_sizes, int n_in,
                              void* d_out, int out_size, void* d_ws, size_t ws_size,
                              hipStream_t stream) {
  const float* x  = (const float*)d_in[0];   // [B=2, C=64, N, 1]
  const int*   ei = (const int*)d_in[1];     // [2, B, N, K] (int64 or int32)
  const float* W1 = (const float*)d_in[2];   // [64, 64]
  const float* b1 = (const float*)d_in[3];   // [64]
  const float* W2 = (const float*)d_in[4];   // [64, 128]
  const float* b2 = (const float*)d_in[5];   // [64]
  float* out = (float*)d_out;                // [B, 64, N, 1]

  const int N = in_sizes[0] / 128;           // B*C = 128
  const int K = in_sizes[1] / (4 * N);       // 2*B = 4

  uint* y = (uint*)d_ws;                     // fp16-pair table [B,N,32 dw] = 12.8 MB

  const int nblk = (N + 63) >> 6;
  const int nblk_pad = (nblk + 3) & ~3;      // 2*nblk_pad divisible by 8
  k1_node_mlp<<<2 * nblk, 256, 0, stream>>>(x, W1, b1, y, N);
  k2_gather_out<<<2 * nblk_pad, 256, 0, stream>>>(x, ei, y, W2, b2, out, N, K, nblk_pad);
}

// Round 8
// 117.892 us; speedup vs baseline: 1.0099x; 1.0099x over previous
//
#include <hip/hip_runtime.h>
#include <cstddef>

typedef unsigned int uint;
typedef _Float16 v8h __attribute__((ext_vector_type(8)));
typedef float v4f __attribute__((ext_vector_type(4)));
typedef __fp16 fp16v2 __attribute__((ext_vector_type(2)));
typedef unsigned short us2v __attribute__((ext_vector_type(2)));

union U32H2 { uint u; fp16v2 g; us2v s; };
union Frag8 { uint4 u4; uint u[4]; v8h h; };  // 8 fp16 = 4 VGPRs (MFMA A/B frag)

// pack two fp32 -> fp16 pair (v_cvt_pkrtz)
__device__ __forceinline__ uint pkh2(float a, float b) {
  U32H2 v; v.g = __builtin_amdgcn_cvt_pkrtz(a, b); return v.u;
}
// packed max on u32-carried fp16 pairs; valid for NON-NEGATIVE fp16 (ReLU'd y):
// fp16 ordering == unsigned ordering => v_pk_max_u16.
__device__ __forceinline__ uint hmax2u(uint a, uint b) {
  U32H2 x, y, r; x.u = a; y.u = b;
  r.s = __builtin_elementwise_max(x.s, y.s);
  return r.u;
}

// ---------------------------------------------------------------------------
// Record layout in d_ws: rec[b*N+n] = 64 dwords (256 B, 256-aligned):
//   dw[ 0..32) = x[b,:,n]  as 32 fp16 pairs (128 B)
//   dw[32..64) = y[b,n,:]  as 32 fp16 pairs (128 B)  [= relu(W1 x + b1)]
// k2's gather touches only the y half = exactly one 128 B cache line/row.
// ---------------------------------------------------------------------------

// K1: builds rec. MFMA 16x16x32_f16; A = W1 (global->frags), B = x tile (LDS).
__global__ __launch_bounds__(256, 6) void k1_node_mlp(
    const float* __restrict__ x, const float* __restrict__ W1,
    const float* __restrict__ b1, uint* __restrict__ rec, int N)
{
  __shared__ __align__(16) uint xlds[64 * 36];  // [n][c-pair], stride 36 dw
  const int t = threadIdx.x;
  const int nblk = (N + 63) >> 6;
  const int b = blockIdx.x / nblk;
  const int n0 = (blockIdx.x % nblk) << 6;
  const int lane = t & 63;
  const int w = t >> 6;          // wave id -> d-strip
  const int node = t >> 2;       // staging row
  const int cg = t & 3;          // 16-channel group
  const bool nvalid = (n0 + node) < N;

  // ---- x staging: thread covers c = cg*16..+15 of node's row; also writes
  // the packed pairs straight to rec's x-half (coalesced 32 B/thread).
  {
    const float* xp = x + (size_t)b * 64 * N + n0 + node;
    float xv[16];
#pragma unroll
    for (int i = 0; i < 16; ++i)
      xv[i] = nvalid ? xp[(size_t)(cg * 16 + i) * N] : 0.0f;
    uint4 p0, p1;
    p0.x = pkh2(xv[0], xv[1]);   p0.y = pkh2(xv[2], xv[3]);
    p0.z = pkh2(xv[4], xv[5]);   p0.w = pkh2(xv[6], xv[7]);
    p1.x = pkh2(xv[8], xv[9]);   p1.y = pkh2(xv[10], xv[11]);
    p1.z = pkh2(xv[12], xv[13]); p1.w = pkh2(xv[14], xv[15]);
    uint* dst = xlds + node * 36 + cg * 8;
    *(uint4*)dst = p0;
    *(uint4*)(dst + 4) = p1;
    if (nvalid) {
      uint* rx = rec + ((size_t)b * N + n0 + node) * 64 + cg * 8;
      *(uint4*)rx = p0;
      *(uint4*)(rx + 4) = p1;
    }
  }

  // ---- A-frags from W1 (L2-hot): row m = lane&15, k = (lane>>4)*8 + j
  Frag8 af[2];
  {
    const int d_row = w * 16 + (lane & 15);
    const int kb = (lane >> 4) * 8;
    const float* wp = W1 + d_row * 64 + kb;
#pragma unroll
    for (int kk = 0; kk < 2; ++kk) {
      const float4 fa = *(const float4*)(wp + kk * 32);
      const float4 fb = *(const float4*)(wp + kk * 32 + 4);
      af[kk].u4.x = pkh2(fa.x, fa.y);
      af[kk].u4.y = pkh2(fa.z, fa.w);
      af[kk].u4.z = pkh2(fb.x, fb.y);
      af[kk].u4.w = pkh2(fb.z, fb.w);
    }
  }
  __syncthreads();

  // ---- MFMA: D[d, n] per wave: d-strip = w*16, 4 n-tiles x 2 k-steps
  const int q = lane >> 4;
  const int cidx = lane & 15;
  v4f acc[4];
  {
    v4f bi;
#pragma unroll
    for (int r = 0; r < 4; ++r) bi[r] = b1[w * 16 + q * 4 + r];
#pragma unroll
    for (int nt = 0; nt < 4; ++nt) acc[nt] = bi;
  }
#pragma unroll
  for (int nt = 0; nt < 4; ++nt) {
#pragma unroll
    for (int kk = 0; kk < 2; ++kk) {
      Frag8 bf;
      bf.u4 = *(const uint4*)(xlds + (nt * 16 + cidx) * 36 + kk * 16 + q * 4);
      acc[nt] = __builtin_amdgcn_mfma_f32_16x16x32_f16(af[kk].h, bf.h, acc[nt], 0, 0, 0);
    }
  }

  // ---- direct epilogue: relu, pack, 8 B store into rec y-half
  // (C-layout: channels d = w*16 + q*4 + r are contiguous per lane)
#pragma unroll
  for (int nt = 0; nt < 4; ++nt) {
    const int n = n0 + nt * 16 + cidx;
    if (n < N) {
      uint2 v;
      v.x = pkh2(fmaxf(acc[nt][0], 0.f), fmaxf(acc[nt][1], 0.f));
      v.y = pkh2(fmaxf(acc[nt][2], 0.f), fmaxf(acc[nt][3], 0.f));
      *(uint2*)(rec + ((size_t)b * N + n) * 64 + 32 + w * 8 + q * 2) = v;
    }
  }
}

// ---------------------------------------------------------------------------
// K2: gather-max over rec y-halves + out = relu(W2 @ [x; m] + b2) via MFMA.
// B-tile [64 n][128 c] fp16 in LDS (stride 272 B); A = W2 global->frags.
// Grid halves: blocks [0,nblk) do b=0, [nblk,2nblk) do b=1 -> each XCD's
// gather working set is one 6.4 MB y-half at a time.
// ---------------------------------------------------------------------------
__global__ __launch_bounds__(256, 4) void k2_gather_out(
    const float* __restrict__ x, const int* __restrict__ eidx,
    const uint* __restrict__ rec, const float* __restrict__ W2,
    const float* __restrict__ b2, float* __restrict__ out, int N, int K)
{
  __shared__ __align__(16) uint blds[64 * 68];  // [n][c-pair], stride 68 dw
  const int t = threadIdx.x;
  const int nblk = (N + 63) >> 6;
  const int g = blockIdx.x;
  const int b = (g >= nblk) ? 1 : 0;
  const int n0 = (g - b * nblk) << 6;
  const int lane = t & 63;
  const int w = t >> 6;
  const int node = t >> 2;   // staging/gather row; 4 adjacent lanes = 4 c-segs
  const int cg = t & 3;
  const int n = n0 + node;

  // int64 vs int32 layout: little-endian int64 => odd words all zero (L2-hot)
  const bool is64 = (__ballot(eidx[2 * lane + 1] == 0) == ~0ull);

  // ---- neighbor indices
  int jj[9];
  const bool act = (n < N) && (K == 9);
  if (act) {
    const size_t r = (size_t)b * N + n;
    if (is64) {
      const uint2* p = (const uint2*)eidx + r * 9;
#pragma unroll
      for (int k = 0; k < 9; ++k) jj[k] = (int)p[k].x;
    } else {
      const int* p = eidx + r * 9;
#pragma unroll
      for (int k = 0; k < 9; ++k) jj[k] = p[k];
    }
  }

  // ---- x staging from rec x-half: coalesced 32 B/thread, already fp16
  {
    const uint* rx = rec + ((size_t)b * N + n0 + node) * 64 + cg * 8;
    const uint4 p0 = *(const uint4*)rx;        // reads within ws even for pad
    const uint4 p1 = *(const uint4*)(rx + 4);  // nodes; masked at store time
    uint* dst = blds + node * 68 + cg * 8;
    *(uint4*)dst = p0;
    *(uint4*)(dst + 4) = p1;
  }

  // ---- A-frags from W2 (global, L2-hot)
  Frag8 af[4];
  {
    const int o_row = w * 16 + (lane & 15);
    const int kb = (lane >> 4) * 8;
    const float* wp = W2 + o_row * 128 + kb;
#pragma unroll
    for (int kk = 0; kk < 4; ++kk) {
      const float4 fa = *(const float4*)(wp + kk * 32);
      const float4 fb = *(const float4*)(wp + kk * 32 + 4);
      af[kk].u4.x = pkh2(fa.x, fa.y);
      af[kk].u4.y = pkh2(fa.z, fa.w);
      af[kk].u4.z = pkh2(fb.x, fb.y);
      af[kk].u4.w = pkh2(fb.z, fb.w);
    }
  }

  // ---- gather-max: thread covers 32 B c-seg cg of its node's 9 neighbor
  // y-rows; two 9-deep uint4 batches (peak 36 VGPRs of payload, no spill).
  uint m[8] = {0, 0, 0, 0, 0, 0, 0, 0};
  if (act) {
    const uint* yb = rec + (size_t)b * N * 64 + 32 + cg * 8;
    uint4 ga[9];
#pragma unroll
    for (int k = 0; k < 9; ++k)
      ga[k] = *(const uint4*)(yb + (size_t)jj[k] * 64);
#pragma unroll
    for (int k = 0; k < 9; ++k) {
      m[0] = hmax2u(m[0], ga[k].x); m[1] = hmax2u(m[1], ga[k].y);
      m[2] = hmax2u(m[2], ga[k].z); m[3] = hmax2u(m[3], ga[k].w);
    }
#pragma unroll
    for (int k = 0; k < 9; ++k)
      ga[k] = *(const uint4*)(yb + (size_t)jj[k] * 64 + 4);
#pragma unroll
    for (int k = 0; k < 9; ++k) {
      m[4] = hmax2u(m[4], ga[k].x); m[5] = hmax2u(m[5], ga[k].y);
      m[6] = hmax2u(m[6], ga[k].z); m[7] = hmax2u(m[7], ga[k].w);
    }
  } else if (n < N) {  // generic-K fallback
    const size_t r = (size_t)b * N + n;
    const uint* yb = rec + (size_t)b * N * 64 + 32 + cg * 8;
    for (int k = 0; k < K; ++k) {
      const int j = is64 ? (int)((const uint2*)eidx + r * K)[k].x
                         : (eidx + r * K)[k];
      const uint* base = yb + (size_t)j * 64;
      const uint4 a0 = *(const uint4*)base, a1 = *(const uint4*)(base + 4);
      m[0] = hmax2u(m[0], a0.x); m[1] = hmax2u(m[1], a0.y);
      m[2] = hmax2u(m[2], a0.z); m[3] = hmax2u(m[3], a0.w);
      m[4] = hmax2u(m[4], a1.x); m[5] = hmax2u(m[5], a1.y);
      m[6] = hmax2u(m[6], a1.z); m[7] = hmax2u(m[7], a1.w);
    }
  }
  {
    uint* dst = blds + node * 68 + 32 + cg * 8;  // c in [64,128)
    uint4 v0; v0.x = m[0]; v0.y = m[1]; v0.z = m[2]; v0.w = m[3];
    uint4 v1; v1.x = m[4]; v1.y = m[5]; v1.z = m[6]; v1.w = m[7];
    *(uint4*)dst = v0;
    *(uint4*)(dst + 4) = v1;
  }
  __syncthreads();

  // ---- MFMA: D[o, n] per wave: o-strip w*16, 4 n-tiles x 4 k-steps
  const int q = lane >> 4;
  const int cidx = lane & 15;
  const int o0 = w * 16;
  v4f acc[4];
  {
    v4f bi;
#pragma unroll
    for (int r = 0; r < 4; ++r) bi[r] = b2[o0 + q * 4 + r];
#pragma unroll
    for (int nt = 0; nt < 4; ++nt) acc[nt] = bi;
  }
#pragma unroll
  for (int nt = 0; nt < 4; ++nt) {
#pragma unroll
    for (int kk = 0; kk < 4; ++kk) {
      Frag8 bf;
      bf.u4 = *(const uint4*)(blds + (nt * 16 + cidx) * 68 + kk * 16 + q * 4);
      acc[nt] = __builtin_amdgcn_mfma_f32_16x16x32_f16(af[kk].h, bf.h, acc[nt], 0, 0, 0);
    }
  }

  // ---- epilogue: relu + store; lanes cidx consecutive -> 64 B segments
#pragma unroll
  for (int nt = 0; nt < 4; ++nt) {
    const int nn = n0 + nt * 16 + cidx;
    if (nn < N) {
#pragma unroll
      for (int r = 0; r < 4; ++r) {
        const int o = o0 + q * 4 + r;
        out[(size_t)(b * 64 + o) * N + nn] = fmaxf(acc[nt][r], 0.f);
      }
    }
  }
}

extern "C" void kernel_launch(void* const* d_in, const int* in_sizes, int n_in,
                              void* d_out, int out_size, void* d_ws, size_t ws_size,
                              hipStream_t stream) {
  const float* x  = (const float*)d_in[0];   // [B=2, C=64, N, 1]
  const int*   ei = (const int*)d_in[1];     // [2, B, N, K] (int64 or int32)
  const float* W1 = (const float*)d_in[2];   // [64, 64]
  const float* b1 = (const float*)d_in[3];   // [64]
  const float* W2 = (const float*)d_in[4];   // [64, 128]
  const float* b2 = (const float*)d_in[5];   // [64]
  float* out = (float*)d_out;                // [B, 64, N, 1]

  const int N = in_sizes[0] / 128;           // B*C = 128
  const int K = in_sizes[1] / (4 * N);       // 2*B = 4

  uint* rec = (uint*)d_ws;                   // [B*N] x 256 B records = 25.6 MB

  const int nblk = (N + 63) >> 6;
  k1_node_mlp<<<2 * nblk, 256, 0, stream>>>(x, W1, b1, rec, N);
  k2_gather_out<<<2 * nblk, 256, 0, stream>>>(x, ei, rec, W2, b2, out, N, K);
}